// Round 1
// baseline (815.591 us; speedup 1.0000x reference)
//
#include <hip/hip_runtime.h>
#include <hip/hip_bf16.h>

typedef float f32x4 __attribute__((ext_vector_type(4)));
typedef short bf16x8 __attribute__((ext_vector_type(8)));
typedef unsigned short u16;

constexpr int T_TOK = 8192;
constexpr int KDIM  = 4096;
constexpr int NDIM  = 4096;
constexpr int NE    = 8;

constexpr int BM = 128, BN = 128, BK = 32;
constexpr int LDK = BK + 8;               // 40 u16 = 80 B row stride (16B-aligned, odd multiple of 16B)
constexpr int NTN = NDIM / BN;            // 32 n-tiles
constexpr int MT_MAX = T_TOK / BM + NE;   // 72 worst-case m-tiles across experts
constexpr int NKT = KDIM / BK;            // 128 k-steps

__device__ __forceinline__ u16 f2bf(float f) {
  unsigned u = __builtin_bit_cast(unsigned, f);
  u += 0x7FFFu + ((u >> 16) & 1u);        // round-to-nearest-even
  return (u16)(u >> 16);
}

__global__ __launch_bounds__(256, 2)
void grouped_gemm_bf16(const float* __restrict__ A, const float* __restrict__ B,
                       float* __restrict__ C, const int* __restrict__ segp,
                       const int* __restrict__ widx)
{
  __shared__ u16 lA[2][BM][LDK];
  __shared__ u16 lB[2][BN][LDK];

  const int nt = blockIdx.x % NTN;
  const int mt = blockIdx.x / NTN;

  // decode (expert, local m-tile) from seg_indptr; uniform across block
  int e = -1, segs = 0, sege = 0, mloc = 0;
  {
    int acc = 0, s_prev = segp[0];
    #pragma unroll
    for (int i = 0; i < NE; ++i) {
      int s_next = segp[i + 1];
      int nti = (s_next - s_prev + BM - 1) / BM;
      if (e < 0 && mt < acc + nti) { e = i; mloc = mt - acc; segs = s_prev; sege = s_next; }
      acc += nti;
      s_prev = s_next;
    }
  }
  if (e < 0) return;  // beyond actual tile count (worst-case grid)

  const int row_base = segs + mloc * BM;
  const int col_base = nt * BN;
  const float* __restrict__ W = B + (long long)widx[e] * NDIM * KDIM;

  const int tid  = threadIdx.x;
  const int lane = tid & 63;
  const int wid  = tid >> 6;
  const int wr   = wid >> 1;   // wave row (0/1) -> 64-row half
  const int wc   = wid & 1;    // wave col (0/1) -> 64-col half

  // staging: thread t owns row (t>>1), 16-float half (t&1) of the 128x32 tile
  const int srow = tid >> 1;
  const int scol = (tid & 1) << 4;
  const int arow = min(row_base + srow, T_TOK - 1);  // clamp ragged tail (stores guarded)
  const float* __restrict__ aptr = A + (long long)arow * KDIM + scol;
  const float* __restrict__ bptr = W + (long long)(col_base + srow) * KDIM + scol;

  f32x4 sa[4], sb[4];
  f32x4 acc[4][4];
  #pragma unroll
  for (int m = 0; m < 4; ++m)
    #pragma unroll
    for (int n = 0; n < 4; ++n)
      acc[m][n] = (f32x4){0.f, 0.f, 0.f, 0.f};

  const int frow = lane & 15;
  const int fk   = (lane >> 4) << 3;

  auto load_tiles = [&](int kt) {
    const float* ap = aptr + kt * BK;
    const float* bp = bptr + kt * BK;
    #pragma unroll
    for (int i = 0; i < 4; ++i) sa[i] = *(const f32x4*)(ap + i * 4);
    #pragma unroll
    for (int i = 0; i < 4; ++i) sb[i] = *(const f32x4*)(bp + i * 4);
  };
  auto conv_write = [&](int buf) {
    u16* wa = &lA[buf][srow][scol];
    u16* wb = &lB[buf][srow][scol];
    bf16x8 p;
    #pragma unroll
    for (int j = 0; j < 8; ++j) p[j] = (short)f2bf(sa[j >> 2][j & 3]);
    *(bf16x8*)(wa) = p;
    #pragma unroll
    for (int j = 0; j < 8; ++j) p[j] = (short)f2bf(sa[2 + (j >> 2)][j & 3]);
    *(bf16x8*)(wa + 8) = p;
    #pragma unroll
    for (int j = 0; j < 8; ++j) p[j] = (short)f2bf(sb[j >> 2][j & 3]);
    *(bf16x8*)(wb) = p;
    #pragma unroll
    for (int j = 0; j < 8; ++j) p[j] = (short)f2bf(sb[2 + (j >> 2)][j & 3]);
    *(bf16x8*)(wb + 8) = p;
  };

  load_tiles(0);
  conv_write(0);
  __syncthreads();

  int cur = 0;
  for (int kt = 0; kt < NKT; ++kt) {
    const bool more = (kt + 1 < NKT);
    if (more) load_tiles(kt + 1);          // global loads for next tile (regs)

    bf16x8 af[4], bfr[4];
    #pragma unroll
    for (int m = 0; m < 4; ++m)
      af[m] = *(const bf16x8*)&lA[cur][wr * 64 + m * 16 + frow][fk];
    #pragma unroll
    for (int n = 0; n < 4; ++n)
      bfr[n] = *(const bf16x8*)&lB[cur][wc * 64 + n * 16 + frow][fk];

    if (more) conv_write(cur ^ 1);         // write NEXT buffer while computing cur

    #pragma unroll
    for (int m = 0; m < 4; ++m)
      #pragma unroll
      for (int n = 0; n < 4; ++n)
        acc[m][n] = __builtin_amdgcn_mfma_f32_16x16x32_bf16(af[m], bfr[n], acc[m][n], 0, 0, 0);

    __syncthreads();
    cur ^= 1;
  }

  // epilogue: C/D layout col = lane&15, row = (lane>>4)*4 + reg
  const int crow0 = row_base + wr * 64;
  const int ccol  = col_base + wc * 64 + (lane & 15);
  const int rsub  = (lane >> 4) << 2;
  #pragma unroll
  for (int m = 0; m < 4; ++m) {
    #pragma unroll
    for (int j = 0; j < 4; ++j) {
      const int r = crow0 + m * 16 + rsub + j;
      if (r < sege) {
        #pragma unroll
        for (int n = 0; n < 4; ++n)
          C[(long long)r * NDIM + ccol + n * 16] = acc[m][n][j];
      }
    }
  }
}

extern "C" void kernel_launch(void* const* d_in, const int* in_sizes, int n_in,
                              void* d_out, int out_size, void* d_ws, size_t ws_size,
                              hipStream_t stream) {
  const float* A   = (const float*)d_in[0];
  const float* B   = (const float*)d_in[1];
  const int* segp  = (const int*)d_in[3];
  const int* widx  = (const int*)d_in[4];
  float* C = (float*)d_out;

  dim3 grid(MT_MAX * NTN);   // 72 * 32 = 2304 blocks; excess blocks self-exit
  grouped_gemm_bf16<<<grid, dim3(256), 0, stream>>>(A, B, C, segp, widx);
}

// Round 2
// 624.534 us; speedup vs baseline: 1.3059x; 1.3059x over previous
//
#include <hip/hip_runtime.h>
#include <hip/hip_bf16.h>

typedef float f32x4 __attribute__((ext_vector_type(4)));
typedef short bf16x8 __attribute__((ext_vector_type(8)));
typedef unsigned short u16;

constexpr int T_TOK = 8192;
constexpr int KDIM  = 4096;
constexpr int NDIM  = 4096;
constexpr int NE    = 8;

constexpr long long TA = (long long)T_TOK * KDIM;        // 33.55M elems (A)
constexpr long long TB = (long long)NE * NDIM * KDIM;    // 134.2M elems (B)

constexpr int BM = 128, BN = 128, BK = 32;
constexpr int NTN = NDIM / BN;            // 32 n-tiles
constexpr int MT_MAX = T_TOK / BM + NE;   // 72 worst-case m-tiles
constexpr int NKT = KDIM / BK;            // 128 k-steps
constexpr int NWG = MT_MAX * NTN;         // 2304 blocks (%8 == 0 -> simple XCD swizzle ok)

__device__ __forceinline__ u16 f2bf(float f) {
  unsigned u = __builtin_bit_cast(unsigned, f);
  u += 0x7FFFu + ((u >> 16) & 1u);        // round-to-nearest-even
  return (u16)(u >> 16);
}

// ---------------- pass 1: fp32 -> bf16 streaming convert (A then B) ----------
__global__ __launch_bounds__(256)
void cvt_bf16(const float* __restrict__ A, const float* __restrict__ B,
              u16* __restrict__ oA, u16* __restrict__ oB) {
  const long long nv = (TA + TB) >> 3;    // 8 floats per item; TA % 8 == 0
  const long long stride = (long long)gridDim.x * blockDim.x;
  for (long long i = (long long)blockIdx.x * blockDim.x + threadIdx.x; i < nv; i += stride) {
    const long long e = i << 3;
    const float* s;
    u16* d;
    if (e < TA) { s = A + e;        d = oA + e; }
    else        { s = B + (e - TA); d = oB + (e - TA); }
    f32x4 v0 = ((const f32x4*)s)[0];
    f32x4 v1 = ((const f32x4*)s)[1];
    bf16x8 p;
    #pragma unroll
    for (int j = 0; j < 4; ++j) p[j]     = (short)f2bf(v0[j]);
    #pragma unroll
    for (int j = 0; j < 4; ++j) p[4 + j] = (short)f2bf(v1[j]);
    *(bf16x8*)d = p;
  }
}

// ---------------- pass 2: bf16 grouped GEMM, m97 structure -------------------
__device__ __forceinline__ void gload16(const u16* g, const u16* l) {
  __builtin_amdgcn_global_load_lds(
      (const __attribute__((address_space(1))) void*)g,
      (__attribute__((address_space(3))) void*)l, 16, 0, 0);
}

__global__ __launch_bounds__(256, 2)
void grouped_gemm_pre(const u16* __restrict__ Abf, const u16* __restrict__ Bbf,
                      float* __restrict__ C, const int* __restrict__ segp,
                      const int* __restrict__ widx)
{
  __shared__ u16 lA[2][BM * BK];   // linear [128][32] bf16, 8 KB per buffer
  __shared__ u16 lB[2][BN * BK];

  // XCD-aware bijective swizzle (NWG % 8 == 0)
  int bid = (int)blockIdx.x;
  bid = (bid & 7) * (NWG / 8) + (bid >> 3);
  const int nt = bid % NTN;
  const int mt = bid / NTN;

  // decode (expert, local m-tile) from seg_indptr; uniform across block
  int e = -1, segs = 0, sege = 0, mloc = 0;
  {
    int acc = 0, s_prev = segp[0];
    #pragma unroll
    for (int i = 0; i < NE; ++i) {
      int s_next = segp[i + 1];
      int nti = (s_next - s_prev + BM - 1) / BM;
      if (e < 0 && mt < acc + nti) { e = i; mloc = mt - acc; segs = s_prev; sege = s_next; }
      acc += nti;
      s_prev = s_next;
    }
  }
  if (e < 0) return;

  const int row_base = segs + mloc * BM;
  const int col_base = nt * BN;
  const u16* __restrict__ W = Bbf + (long long)widx[e] * ((long long)NDIM * KDIM);

  const int tid  = threadIdx.x;
  const int lane = tid & 63;
  const int wid  = tid >> 6;
  const int wr   = wid >> 1;   // wave row (0/1) -> 64-row half
  const int wc   = wid & 1;    // wave col (0/1) -> 64-col half

  // staging: wave w instr i covers tile elems [w*1024 + i*512 + lane*8, +8)
  // -> row = w*32 + i*16 + (lane>>2), col = (lane&3)*8
  const int r0 = wid * 32 + (lane >> 2);
  const int c0 = (lane & 3) * 8;
  const int rA0 = min(row_base + r0,      T_TOK - 1);   // clamp ragged tail
  const int rA1 = min(row_base + r0 + 16, T_TOK - 1);
  const u16* gA0 = Abf + (long long)rA0 * KDIM + c0;
  const u16* gA1 = Abf + (long long)rA1 * KDIM + c0;
  const u16* gB0 = W + (long long)(col_base + r0)      * KDIM + c0;
  const u16* gB1 = W + (long long)(col_base + r0 + 16) * KDIM + c0;

  f32x4 acc[4][4];
  #pragma unroll
  for (int m = 0; m < 4; ++m)
    #pragma unroll
    for (int n = 0; n < 4; ++n)
      acc[m][n] = (f32x4){0.f, 0.f, 0.f, 0.f};

  const int frow = lane & 15;
  const int fke  = (lane >> 4) * 8;    // k-offset in elems for ds_read_b128

  auto STAGE = [&](int buf) {
    gload16(gA0, &lA[buf][wid * 1024]);
    gload16(gA1, &lA[buf][wid * 1024 + 512]);
    gload16(gB0, &lB[buf][wid * 1024]);
    gload16(gB1, &lB[buf][wid * 1024 + 512]);
    gA0 += BK; gA1 += BK; gB0 += BK; gB1 += BK;
  };

  STAGE(0);
  __syncthreads();   // compiler drains vmcnt(0) before s_barrier

  int cur = 0;
  for (int kt = 0; kt < NKT; ++kt) {
    if (kt + 1 < NKT) STAGE(cur ^ 1);    // prefetch next tile into other buffer

    bf16x8 af[4], bfr[4];
    #pragma unroll
    for (int m = 0; m < 4; ++m)
      af[m] = *(const bf16x8*)&lA[cur][(wr * 64 + m * 16 + frow) * BK + fke];
    #pragma unroll
    for (int n = 0; n < 4; ++n)
      bfr[n] = *(const bf16x8*)&lB[cur][(wc * 64 + n * 16 + frow) * BK + fke];

    #pragma unroll
    for (int m = 0; m < 4; ++m)
      #pragma unroll
      for (int n = 0; n < 4; ++n)
        acc[m][n] = __builtin_amdgcn_mfma_f32_16x16x32_bf16(af[m], bfr[n], acc[m][n], 0, 0, 0);

    __syncthreads();
    cur ^= 1;
  }

  // epilogue: C/D layout col = lane&15, row = (lane>>4)*4 + reg
  const int crow0 = row_base + wr * 64;
  const int ccol  = col_base + wc * 64 + (lane & 15);
  const int rsub  = (lane >> 4) << 2;
  #pragma unroll
  for (int m = 0; m < 4; ++m) {
    #pragma unroll
    for (int j = 0; j < 4; ++j) {
      const int r = crow0 + m * 16 + rsub + j;
      if (r < sege) {
        #pragma unroll
        for (int n = 0; n < 4; ++n)
          C[(long long)r * NDIM + ccol + n * 16] = acc[m][n][j];
      }
    }
  }
}

// ---------------- fallback (round-1 fused convert+GEMM) ----------------------
constexpr int LDK = BK + 8;

__global__ __launch_bounds__(256, 2)
void grouped_gemm_fused(const float* __restrict__ A, const float* __restrict__ B,
                        float* __restrict__ C, const int* __restrict__ segp,
                        const int* __restrict__ widx)
{
  __shared__ u16 lA[2][BM][LDK];
  __shared__ u16 lB[2][BN][LDK];

  const int nt = blockIdx.x % NTN;
  const int mt = blockIdx.x / NTN;

  int e = -1, segs = 0, sege = 0, mloc = 0;
  {
    int acc = 0, s_prev = segp[0];
    #pragma unroll
    for (int i = 0; i < NE; ++i) {
      int s_next = segp[i + 1];
      int nti = (s_next - s_prev + BM - 1) / BM;
      if (e < 0 && mt < acc + nti) { e = i; mloc = mt - acc; segs = s_prev; sege = s_next; }
      acc += nti;
      s_prev = s_next;
    }
  }
  if (e < 0) return;

  const int row_base = segs + mloc * BM;
  const int col_base = nt * BN;
  const float* __restrict__ W = B + (long long)widx[e] * NDIM * KDIM;

  const int tid  = threadIdx.x;
  const int lane = tid & 63;
  const int wid  = tid >> 6;
  const int wr   = wid >> 1;
  const int wc   = wid & 1;

  const int srow = tid >> 1;
  const int scol = (tid & 1) << 4;
  const int arow = min(row_base + srow, T_TOK - 1);
  const float* __restrict__ aptr = A + (long long)arow * KDIM + scol;
  const float* __restrict__ bptr = W + (long long)(col_base + srow) * KDIM + scol;

  f32x4 sa[4], sb[4];
  f32x4 acc[4][4];
  #pragma unroll
  for (int m = 0; m < 4; ++m)
    #pragma unroll
    for (int n = 0; n < 4; ++n)
      acc[m][n] = (f32x4){0.f, 0.f, 0.f, 0.f};

  const int frow = lane & 15;
  const int fk   = (lane >> 4) << 3;

  auto load_tiles = [&](int kt) {
    const float* ap = aptr + kt * BK;
    const float* bp = bptr + kt * BK;
    #pragma unroll
    for (int i = 0; i < 4; ++i) sa[i] = *(const f32x4*)(ap + i * 4);
    #pragma unroll
    for (int i = 0; i < 4; ++i) sb[i] = *(const f32x4*)(bp + i * 4);
  };
  auto conv_write = [&](int buf) {
    u16* wa = &lA[buf][srow][scol];
    u16* wb = &lB[buf][srow][scol];
    bf16x8 p;
    #pragma unroll
    for (int j = 0; j < 8; ++j) p[j] = (short)f2bf(sa[j >> 2][j & 3]);
    *(bf16x8*)(wa) = p;
    #pragma unroll
    for (int j = 0; j < 8; ++j) p[j] = (short)f2bf(sa[2 + (j >> 2)][j & 3]);
    *(bf16x8*)(wa + 8) = p;
    #pragma unroll
    for (int j = 0; j < 8; ++j) p[j] = (short)f2bf(sb[j >> 2][j & 3]);
    *(bf16x8*)(wb) = p;
    #pragma unroll
    for (int j = 0; j < 8; ++j) p[j] = (short)f2bf(sb[2 + (j >> 2)][j & 3]);
    *(bf16x8*)(wb + 8) = p;
  };

  load_tiles(0);
  conv_write(0);
  __syncthreads();

  int cur = 0;
  for (int kt = 0; kt < NKT; ++kt) {
    const bool more = (kt + 1 < NKT);
    if (more) load_tiles(kt + 1);

    bf16x8 af[4], bfr[4];
    #pragma unroll
    for (int m = 0; m < 4; ++m)
      af[m] = *(const bf16x8*)&lA[cur][wr * 64 + m * 16 + frow][fk];
    #pragma unroll
    for (int n = 0; n < 4; ++n)
      bfr[n] = *(const bf16x8*)&lB[cur][wc * 64 + n * 16 + frow][fk];

    if (more) conv_write(cur ^ 1);

    #pragma unroll
    for (int m = 0; m < 4; ++m)
      #pragma unroll
      for (int n = 0; n < 4; ++n)
        acc[m][n] = __builtin_amdgcn_mfma_f32_16x16x32_bf16(af[m], bfr[n], acc[m][n], 0, 0, 0);

    __syncthreads();
    cur ^= 1;
  }

  const int crow0 = row_base + wr * 64;
  const int ccol  = col_base + wc * 64 + (lane & 15);
  const int rsub  = (lane >> 4) << 2;
  #pragma unroll
  for (int m = 0; m < 4; ++m) {
    #pragma unroll
    for (int j = 0; j < 4; ++j) {
      const int r = crow0 + m * 16 + rsub + j;
      if (r < sege) {
        #pragma unroll
        for (int n = 0; n < 4; ++n)
          C[(long long)r * NDIM + ccol + n * 16] = acc[m][n][j];
      }
    }
  }
}

extern "C" void kernel_launch(void* const* d_in, const int* in_sizes, int n_in,
                              void* d_out, int out_size, void* d_ws, size_t ws_size,
                              hipStream_t stream) {
  const float* A   = (const float*)d_in[0];
  const float* B   = (const float*)d_in[1];
  const int* segp  = (const int*)d_in[3];
  const int* widx  = (const int*)d_in[4];
  float* C = (float*)d_out;

  const size_t need = (size_t)(TA + TB) * sizeof(u16);   // 320 MB
  if (ws_size >= need) {
    u16* oA = (u16*)d_ws;
    u16* oB = oA + TA;
    cvt_bf16<<<dim3(2048), dim3(256), 0, stream>>>(A, B, oA, oB);
    grouped_gemm_pre<<<dim3(NWG), dim3(256), 0, stream>>>(oA, oB, C, segp, widx);
  } else {
    grouped_gemm_fused<<<dim3(NWG), dim3(256), 0, stream>>>(A, B, C, segp, widx);
  }
}

// Round 4
// 491.270 us; speedup vs baseline: 1.6602x; 1.2713x over previous
//
#include <hip/hip_runtime.h>
#include <hip/hip_bf16.h>

typedef float f32x4 __attribute__((ext_vector_type(4)));
typedef short bf16x8 __attribute__((ext_vector_type(8)));
typedef unsigned short u16;

constexpr int T_TOK = 8192;
constexpr int KDIM  = 4096;
constexpr int NDIM  = 4096;
constexpr int NE    = 8;

constexpr long long TA = (long long)T_TOK * KDIM;
constexpr long long TB = (long long)NE * NDIM * KDIM;

__device__ __forceinline__ u16 f2bf(float f) {
  unsigned u = __builtin_bit_cast(unsigned, f);
  u += 0x7FFFu + ((u >> 16) & 1u);
  return (u16)(u >> 16);
}

// ---------------- pass 1: fp32 -> bf16 streaming convert ---------------------
__global__ __launch_bounds__(256)
void cvt_bf16(const float* __restrict__ A, const float* __restrict__ B,
              u16* __restrict__ oA, u16* __restrict__ oB) {
  const long long nv = (TA + TB) >> 3;
  const long long stride = (long long)gridDim.x * blockDim.x;
  for (long long i = (long long)blockIdx.x * blockDim.x + threadIdx.x; i < nv; i += stride) {
    const long long e = i << 3;
    const float* s;
    u16* d;
    if (e < TA) { s = A + e;        d = oA + e; }
    else        { s = B + (e - TA); d = oB + (e - TA); }
    f32x4 v0 = ((const f32x4*)s)[0];
    f32x4 v1 = ((const f32x4*)s)[1];
    bf16x8 p;
    #pragma unroll
    for (int j = 0; j < 4; ++j) p[j]     = (short)f2bf(v0[j]);
    #pragma unroll
    for (int j = 0; j < 4; ++j) p[4 + j] = (short)f2bf(v1[j]);
    *(bf16x8*)d = p;
  }
}

// ---------------- pass 2: 256x256 8-wave deep-pipelined grouped GEMM ---------
__device__ __forceinline__ void gload16(const u16* g, const u16* l) {
  __builtin_amdgcn_global_load_lds(
      (const __attribute__((address_space(1))) void*)g,
      (__attribute__((address_space(3))) void*)l, 16, 0, 0);
}

constexpr int BM2 = 256, BN2 = 256, BK2 = 64;
constexpr int NKT2 = KDIM / BK2;          // 64 k-tiles
constexpr int NTN2 = NDIM / BN2;          // 16 n-tiles
constexpr int MT2  = T_TOK / BM2 + NE;    // 40 worst-case m-tiles
constexpr int NWG2 = MT2 * NTN2;          // 640 (%8==0 -> simple XCD swizzle)
constexpr int ASZ  = BM2 * BK2;           // 16384 elems per buffer per operand
constexpr int HSZ  = ASZ / 2;             // 8192 elems (128-row half)

#define FBAR() do { asm volatile("" ::: "memory"); __builtin_amdgcn_s_barrier(); asm volatile("" ::: "memory"); } while (0)

__global__ __launch_bounds__(512, 2)
void gg8(const u16* __restrict__ Abf, const u16* __restrict__ Bbf,
         float* __restrict__ C, const int* __restrict__ segp,
         const int* __restrict__ widx)
{
  extern __shared__ u16 sm[];
  u16* sA = sm;               // [2][2][8192]  (buf, half, elems)
  u16* sB = sm + 2 * ASZ;

  int bid = (int)blockIdx.x;
  bid = (bid & 7) * (NWG2 / 8) + (bid >> 3);   // XCD-aware bijective swizzle
  const int nt = bid % NTN2;
  const int mt = bid / NTN2;

  int e = -1, segs = 0, sege = 0, mloc = 0;
  {
    int acc0 = 0, sp = segp[0];
    #pragma unroll
    for (int i = 0; i < NE; ++i) {
      int sn = segp[i + 1];
      int nti = (sn - sp + BM2 - 1) / BM2;
      if (e < 0 && mt < acc0 + nti) { e = i; mloc = mt - acc0; segs = sp; sege = sn; }
      acc0 += nti; sp = sn;
    }
  }
  if (e < 0) return;

  const int row_base = segs + mloc * BM2;
  const int col_base = nt * BN2;
  const u16* __restrict__ W = Bbf + (long long)widx[e] * ((long long)NDIM * KDIM);

  const int tid = threadIdx.x, lane = tid & 63, wid = tid >> 6;
  const int wr = wid >> 2, wc = wid & 3;

  // ---- staging addresses: linear LDS dest, inverse-swizzled global source ---
  // LDS half = 128 rows x 64 cols bf16 (128B rows, 8x16B granules/row).
  // LDS granule (row, g) holds global col-granule g ^ (row&7)  [involution].
  const int sg = (((lane & 7) ^ (lane >> 3)) << 3);   // src col elems
  const int rr = wid * 8 + (lane >> 3);               // row within 64-row block
  int oA[2][2], oB[2][2];
  #pragma unroll
  for (int h = 0; h < 2; ++h)
    #pragma unroll
    for (int i = 0; i < 2; ++i) {
      oA[h][i] = min(row_base + h * 128 + i * 64 + rr, T_TOK - 1) * KDIM + sg;
      oB[h][i] = (col_base + h * 128 + i * 64 + rr) * KDIM + sg;
    }

  // ---- fragment-read offsets (swizzled): granule G' = G ^ (row&7) ----------
  const int g0  = (lane >> 4) ^ (lane & 7);
  const int g1  = g0 ^ 4;                              // ksub=1 (+32 elems logical)
  const int rA0 = (wr * 64 + (lane & 15)) * BK2 + g0 * 8;
  const int rA1 = (wr * 64 + (lane & 15)) * BK2 + g1 * 8;
  const int rB0 = (wc * 32 + (lane & 15)) * BK2 + g0 * 8;
  const int rB1 = (wc * 32 + (lane & 15)) * BK2 + g1 * 8;

  f32x4 acc[8][4];
  #pragma unroll
  for (int m = 0; m < 8; ++m)
    #pragma unroll
    for (int n = 0; n < 4; ++n)
      acc[m][n] = (f32x4){0.f, 0.f, 0.f, 0.f};

  bf16x8 aF[4][2], bF0[2][2], bF1[2][2];

  auto STGA = [&](int bbuf, int h, int t) __attribute__((always_inline)) {
    gload16(Abf + oA[h][0] + t * BK2, sA + bbuf * ASZ + h * HSZ + wid * 512);
    gload16(Abf + oA[h][1] + t * BK2, sA + bbuf * ASZ + h * HSZ + 4096 + wid * 512);
  };
  auto STGB = [&](int bbuf, int h, int t) __attribute__((always_inline)) {
    gload16(W + oB[h][0] + t * BK2, sB + bbuf * ASZ + h * HSZ + wid * 512);
    gload16(W + oB[h][1] + t * BK2, sB + bbuf * ASZ + h * HSZ + 4096 + wid * 512);
  };
  auto LDA = [&](int bbuf, int mh) __attribute__((always_inline)) {
    #pragma unroll
    for (int j = 0; j < 4; ++j) {
      const u16* p = sA + bbuf * ASZ + mh * HSZ + j * 16 * BK2;
      aF[j][0] = *(const bf16x8*)(p + rA0);
      aF[j][1] = *(const bf16x8*)(p + rA1);
    }
  };
  auto LDB = [&](int bbuf, int nh, bf16x8 (&bF)[2][2]) __attribute__((always_inline)) {
    #pragma unroll
    for (int i = 0; i < 2; ++i) {
      const u16* p = sB + bbuf * ASZ + nh * HSZ + i * 16 * BK2;
      bF[i][0] = *(const bf16x8*)(p + rB0);
      bF[i][1] = *(const bf16x8*)(p + rB1);
    }
  };
  auto MF = [&](int mh, int nh, bf16x8 (&bF)[2][2]) __attribute__((always_inline)) {
    __builtin_amdgcn_s_setprio(1);
    #pragma unroll
    for (int j = 0; j < 4; ++j)
      #pragma unroll
      for (int i = 0; i < 2; ++i) {
        acc[mh * 4 + j][nh * 2 + i] = __builtin_amdgcn_mfma_f32_16x16x32_bf16(
            aF[j][0], bF[i][0], acc[mh * 4 + j][nh * 2 + i], 0, 0, 0);
        acc[mh * 4 + j][nh * 2 + i] = __builtin_amdgcn_mfma_f32_16x16x32_bf16(
            aF[j][1], bF[i][1], acc[mh * 4 + j][nh * 2 + i], 0, 0, 0);
      }
    __builtin_amdgcn_s_setprio(0);
  };

  // prologue: tile0 (all 4 halves) + A_lo(1), B_lo(1); wait tile0 landed
  STGA(0, 0, 0); STGB(0, 0, 0); STGA(0, 1, 0); STGB(0, 1, 0);
  STGA(1, 0, 1); STGB(1, 0, 1);
  asm volatile("s_waitcnt vmcnt(4)" ::: "memory");
  FBAR();

  // steady state invariant at tile-t start: tile t fully landed; in flight =
  // {A_lo(t+1), B_lo(t+1)} (4 per-wave loads). One counted vmcnt per tile.
  //
  // TAIL FIX (round-3 bug): at t = NKT2-2, p3/p4 skip their STGs, so only
  // 8 ops are outstanding at the tile-end wait; vmcnt(4) would leave
  // {A_hi,B_hi}(NKT2-1) in flight while the last iteration reads them.
  // Drain with vmcnt(0) for the last two iterations instead.
  for (int t = 0; t < NKT2; ++t) {
    const int bb = t & 1, nb = bb ^ 1;
    // p1 (mh0,nh0): reads A_lo,B_lo(t); stages A_hi(t+1) [nb, read at t-1 p3]
    LDA(bb, 0); LDB(bb, 0, bF0);
    if (t + 1 < NKT2) STGA(nb, 1, t + 1);
    MF(0, 0, bF0);
    FBAR();
    // p2 (mh0,nh1): reads B_hi(t); stages B_hi(t+1) [nb, read at t-1 p2]
    LDB(bb, 1, bF1);
    if (t + 1 < NKT2) STGB(nb, 1, t + 1);
    MF(0, 1, bF1);
    FBAR();
    // p3 (mh1,nh0): reads A_hi(t); stages A_lo(t+2) [bb A_lo, last read p1]
    LDA(bb, 1);
    if (t + 2 < NKT2) STGA(bb, 0, t + 2);
    MF(1, 0, bF0);
    FBAR();
    // p4 (mh1,nh1): no new reads; stages B_lo(t+2) [bb B_lo, last read p1]
    if (t + 2 < NKT2) STGB(bb, 0, t + 2);
    MF(1, 1, bF1);
    if (t + 2 < NKT2) {
      asm volatile("s_waitcnt vmcnt(4)" ::: "memory");  // tile t+1 fully landed
    } else {
      asm volatile("s_waitcnt vmcnt(0)" ::: "memory");  // tail: drain all
    }
    FBAR();
  }

  // epilogue: C/D per 16x16 frag: col=lane&15, row=(lane>>4)*4+reg
  #pragma unroll
  for (int m = 0; m < 8; ++m) {
    const int r0 = row_base + (m >> 2) * 128 + wr * 64 + (m & 3) * 16 + ((lane >> 4) << 2);
    #pragma unroll
    for (int j = 0; j < 4; ++j) {
      const int r = r0 + j;
      if (r < sege) {
        float* cp = C + (long long)r * NDIM + col_base + (lane & 15);
        #pragma unroll
        for (int n = 0; n < 4; ++n)
          cp[(n >> 1) * 128 + wc * 32 + (n & 1) * 16] = acc[m][n][j];
      }
    }
  }
}

// ---------------- fallback (round-1 fused convert+GEMM) ----------------------
constexpr int BM = 128, BN = 128, BK = 32;
constexpr int LDKF = BK + 8;
constexpr int NTN = NDIM / BN;
constexpr int MT_MAX = T_TOK / BM + NE;
constexpr int NKT = KDIM / BK;
constexpr int NWG = MT_MAX * NTN;

__global__ __launch_bounds__(256, 2)
void grouped_gemm_fused(const float* __restrict__ A, const float* __restrict__ B,
                        float* __restrict__ C, const int* __restrict__ segp,
                        const int* __restrict__ widx)
{
  __shared__ u16 lA[2][BM][LDKF];
  __shared__ u16 lB[2][BN][LDKF];

  const int nt = blockIdx.x % NTN;
  const int mt = blockIdx.x / NTN;

  int e = -1, segs = 0, sege = 0, mloc = 0;
  {
    int acc0 = 0, sp = segp[0];
    #pragma unroll
    for (int i = 0; i < NE; ++i) {
      int sn = segp[i + 1];
      int nti = (sn - sp + BM - 1) / BM;
      if (e < 0 && mt < acc0 + nti) { e = i; mloc = mt - acc0; segs = sp; sege = sn; }
      acc0 += nti; sp = sn;
    }
  }
  if (e < 0) return;

  const int row_base = segs + mloc * BM;
  const int col_base = nt * BN;
  const float* __restrict__ W = B + (long long)widx[e] * NDIM * KDIM;

  const int tid  = threadIdx.x;
  const int lane = tid & 63;
  const int wid  = tid >> 6;
  const int wr   = wid >> 1;
  const int wc   = wid & 1;

  const int srow = tid >> 1;
  const int scol = (tid & 1) << 4;
  const int arow = min(row_base + srow, T_TOK - 1);
  const float* __restrict__ aptr = A + (long long)arow * KDIM + scol;
  const float* __restrict__ bptr = W + (long long)(col_base + srow) * KDIM + scol;

  f32x4 sa[4], sb[4];
  f32x4 acc[4][4];
  #pragma unroll
  for (int m = 0; m < 4; ++m)
    #pragma unroll
    for (int n = 0; n < 4; ++n)
      acc[m][n] = (f32x4){0.f, 0.f, 0.f, 0.f};

  const int frow = lane & 15;
  const int fk   = (lane >> 4) << 3;

  auto load_tiles = [&](int kt) {
    const float* ap = aptr + kt * BK;
    const float* bp = bptr + kt * BK;
    #pragma unroll
    for (int i = 0; i < 4; ++i) sa[i] = *(const f32x4*)(ap + i * 4);
    #pragma unroll
    for (int i = 0; i < 4; ++i) sb[i] = *(const f32x4*)(bp + i * 4);
  };
  auto conv_write = [&](int buf) {
    u16* wa = &lA[buf][srow][scol];
    u16* wb = &lB[buf][srow][scol];
    bf16x8 p;
    #pragma unroll
    for (int j = 0; j < 8; ++j) p[j] = (short)f2bf(sa[j >> 2][j & 3]);
    *(bf16x8*)(wa) = p;
    #pragma unroll
    for (int j = 0; j < 8; ++j) p[j] = (short)f2bf(sa[2 + (j >> 2)][j & 3]);
    *(bf16x8*)(wa + 8) = p;
    #pragma unroll
    for (int j = 0; j < 8; ++j) p[j] = (short)f2bf(sb[j >> 2][j & 3]);
    *(bf16x8*)(wb) = p;
    #pragma unroll
    for (int j = 0; j < 8; ++j) p[j] = (short)f2bf(sb[2 + (j >> 2)][j & 3]);
    *(bf16x8*)(wb + 8) = p;
  };

  load_tiles(0);
  conv_write(0);
  __syncthreads();

  int cur = 0;
  for (int kt = 0; kt < NKT; ++kt) {
    const bool more = (kt + 1 < NKT);
    if (more) load_tiles(kt + 1);

    bf16x8 af[4], bfr[4];
    #pragma unroll
    for (int m = 0; m < 4; ++m)
      af[m] = *(const bf16x8*)&lA[cur][wr * 64 + m * 16 + frow][fk];
    #pragma unroll
    for (int n = 0; n < 4; ++n)
      bfr[n] = *(const bf16x8*)&lB[cur][wc * 64 + n * 16 + frow][fk];

    if (more) conv_write(cur ^ 1);

    #pragma unroll
    for (int m = 0; m < 4; ++m)
      #pragma unroll
      for (int n = 0; n < 4; ++n)
        acc[m][n] = __builtin_amdgcn_mfma_f32_16x16x32_bf16(af[m], bfr[n], acc[m][n], 0, 0, 0);

    __syncthreads();
    cur ^= 1;
  }

  const int crow0 = row_base + wr * 64;
  const int ccol  = col_base + wc * 64 + (lane & 15);
  const int rsub  = (lane >> 4) << 2;
  #pragma unroll
  for (int m = 0; m < 4; ++m) {
    #pragma unroll
    for (int j = 0; j < 4; ++j) {
      const int r = crow0 + m * 16 + rsub + j;
      if (r < sege) {
        #pragma unroll
        for (int n = 0; n < 4; ++n)
          C[(long long)r * NDIM + ccol + n * 16] = acc[m][n][j];
      }
    }
  }
}

extern "C" void kernel_launch(void* const* d_in, const int* in_sizes, int n_in,
                              void* d_out, int out_size, void* d_ws, size_t ws_size,
                              hipStream_t stream) {
  const float* A   = (const float*)d_in[0];
  const float* B   = (const float*)d_in[1];
  const int* segp  = (const int*)d_in[3];
  const int* widx  = (const int*)d_in[4];
  float* C = (float*)d_out;

  const size_t need = (size_t)(TA + TB) * sizeof(u16);   // 320 MB
  if (ws_size >= need) {
    u16* oA = (u16*)d_ws;
    u16* oB = oA + TA;
    cvt_bf16<<<dim3(2048), dim3(256), 0, stream>>>(A, B, oA, oB);
    (void)hipFuncSetAttribute((const void*)gg8,
                              hipFuncAttributeMaxDynamicSharedMemorySize,
                              2 * 2 * ASZ * (int)sizeof(u16));
    gg8<<<dim3(NWG2), dim3(512), 2 * 2 * ASZ * sizeof(u16), stream>>>(oA, oB, C, segp, widx);
  } else {
    grouped_gemm_fused<<<dim3(NWG), dim3(256), 0, stream>>>(A, B, C, segp, widx);
  }
}